// Round 1
// baseline (60.536 us; speedup 1.0000x reference)
//
#include <hip/hip_runtime.h>

// Problem constants (match reference)
#define HH    128
#define WWID  128
#define CCH   3
#define PP    16
#define NIMG  64
#define NPROJ 512

// total patch elements = NPROJ*NIMG*CCH*PP*PP = 25,165,824
#define TOTAL_ELEMS 25165824
#define TOTAL_VEC4  (TOTAL_ELEMS / 4)   // 6,291,456

__global__ __launch_bounds__(256) void cut_patches_kernel(
    const float* __restrict__ imgs,
    const int*   __restrict__ pih,
    const int*   __restrict__ piw,
    float*       __restrict__ out_patches,
    float*       __restrict__ out_inds)
{
    int t = blockIdx.x * blockDim.x + threadIdx.x;
    if (t >= TOTAL_VEC4) return;

    int e = t << 2;                 // first element index of this float4
    // decompose e -> (proj, n, c, ph, pw)
    int pw  = e & 15;               // P = 16
    int tmp = e >> 4;
    int ph  = tmp & 15;
    tmp >>= 4;
    int c   = tmp % 3;
    tmp    /= 3;
    int n   = tmp & 63;             // N = 64
    int proj = tmp >> 6;

    int h0 = pih[proj];
    int w0 = piw[proj];

    int hh = h0 + ph;
    if (hh >= HH) hh -= HH;         // periodic wrap (h0<128, ph<16 -> one subtract)

    // base linear index without the w component:
    // lin = ww + W*hh + (H*W)*c + (C*H*W)*n
    int base = hh * WWID + c * (HH * WWID) + n * (CCH * HH * WWID);

    float4 vals, inds;
    float* pv = reinterpret_cast<float*>(&vals);
    float* pi = reinterpret_cast<float*>(&inds);
#pragma unroll
    for (int i = 0; i < 4; ++i) {
        int w = w0 + pw + i;
        if (w >= WWID) w -= WWID;   // one subtract suffices (w0<128, pw+i<=18)
        int lin = base + w;
        pv[i] = imgs[lin];
        pi[i] = (float)lin;         // exact: lin < 2^24
    }

    reinterpret_cast<float4*>(out_patches)[t] = vals;
    reinterpret_cast<float4*>(out_inds)[t]    = inds;
}

extern "C" void kernel_launch(void* const* d_in, const int* in_sizes, int n_in,
                              void* d_out, int out_size, void* d_ws, size_t ws_size,
                              hipStream_t stream) {
    const float* imgs = (const float*)d_in[0];
    const int*   pih  = (const int*)d_in[1];
    const int*   piw  = (const int*)d_in[2];

    float* out_patches = (float*)d_out;
    float* out_inds    = (float*)d_out + TOTAL_ELEMS;

    const int block = 256;
    const int grid  = (TOTAL_VEC4 + block - 1) / block;   // 24,576 blocks
    cut_patches_kernel<<<grid, block, 0, stream>>>(imgs, pih, piw, out_patches, out_inds);
}

// Round 3
// 58.460 us; speedup vs baseline: 1.0355x; 1.0355x over previous
//
#include <hip/hip_runtime.h>

// Problem constants (match reference)
#define HH    128
#define WWID  128
#define CCH   3
#define PP    16
#define NIMG  64
#define NPROJ 512
#define NXCD  8
#define IMGS_PER_XCD (NIMG / NXCD)     // 8 images -> 1.5 MB, fits 4 MB per-XCD L2

// total patch elements = NPROJ*NIMG*CCH*PP*PP = 25,165,824
#define TOTAL_ELEMS 25165824
// per-XCD slice: NPROJ * IMGS_PER_XCD * CCH * PP * PP elements
#define SLICE_ELEMS (NPROJ * IMGS_PER_XCD * CCH * PP * PP)  // 3,145,728
#define SLICE_VEC4  (SLICE_ELEMS / 4)                       // 786,432
#define BLOCKS_PER_SLICE (SLICE_VEC4 / 256)                 // 3,072

typedef float f32x4 __attribute__((ext_vector_type(4)));   // native vector for nt-store

__global__ __launch_bounds__(256) void cut_patches_kernel(
    const float* __restrict__ imgs,
    const int*   __restrict__ pih,
    const int*   __restrict__ piw,
    float*       __restrict__ out_patches,
    float*       __restrict__ out_inds)
{
    // XCD-partitioned mapping: blockIdx.x % 8 ~ XCD id (dispatch round-robin).
    // Each XCD slice covers images [xcd*8, xcd*8+8) for ALL projections, so its
    // gather working set is 8 imgs * 3 ch * 64KB = 1.5 MB -> L2-resident.
    int xcd = blockIdx.x & (NXCD - 1);
    int bid = blockIdx.x >> 3;                   // 0 .. 3071
    int s   = bid * blockDim.x + threadIdx.x;    // 0 .. SLICE_VEC4-1

    int e = s << 2;                  // first element (within slice)
    // slice decomposition: (proj, nl, c, ph, pw), pw fastest
    int pw  = e & 15;
    int tmp = e >> 4;
    int ph  = tmp & 15;
    tmp >>= 4;
    int c   = tmp % 3;
    tmp    /= 3;
    int nl  = tmp & (IMGS_PER_XCD - 1);
    int proj = tmp >> 3;
    int n   = (xcd << 3) | nl;

    int h0 = pih[proj];
    int w0 = piw[proj];

    int hh = h0 + ph;
    if (hh >= HH) hh -= HH;          // periodic wrap (one subtract suffices)

    // lin = ww + W*hh + (H*W)*c + (C*H*W)*n
    int base = hh * WWID + c * (HH * WWID) + n * (CCH * HH * WWID);

    f32x4 vals, inds;
#pragma unroll
    for (int i = 0; i < 4; ++i) {
        int w = w0 + pw + i;
        if (w >= WWID) w -= WWID;    // one subtract (w0<128, pw+i<=18)
        int lin = base + w;
        vals[i] = imgs[lin];         // L2-resident gather
        inds[i] = (float)lin;        // exact: lin < 2^24
    }

    // output element index (global layout: [proj][n][c][ph][pw])
    int oelem = (((proj * NIMG + n) * CCH + c) << 8) | (ph << 4) | pw;
    int ovec  = oelem >> 2;

    // Non-temporal: don't let the 201 MB store stream evict the image tiles.
    __builtin_nontemporal_store(vals, reinterpret_cast<f32x4*>(out_patches) + ovec);
    __builtin_nontemporal_store(inds, reinterpret_cast<f32x4*>(out_inds) + ovec);
}

extern "C" void kernel_launch(void* const* d_in, const int* in_sizes, int n_in,
                              void* d_out, int out_size, void* d_ws, size_t ws_size,
                              hipStream_t stream) {
    const float* imgs = (const float*)d_in[0];
    const int*   pih  = (const int*)d_in[1];
    const int*   piw  = (const int*)d_in[2];

    float* out_patches = (float*)d_out;
    float* out_inds    = (float*)d_out + TOTAL_ELEMS;

    const int block = 256;
    const int grid  = BLOCKS_PER_SLICE * NXCD;   // 24,576 blocks
    cut_patches_kernel<<<grid, block, 0, stream>>>(imgs, pih, piw, out_patches, out_inds);
}

// Round 4
// 40.752 us; speedup vs baseline: 1.4855x; 1.4345x over previous
//
#include <hip/hip_runtime.h>

// Problem constants (match reference)
#define HH    128
#define WWID  128
#define CCH   3
#define PP    16
#define NIMG  64
#define NPROJ 512
#define NXCD  8
#define IMGS_PER_XCD (NIMG / NXCD)

#define TOTAL_ELEMS 25165824
#define SLICE_ELEMS (NPROJ * IMGS_PER_XCD * CCH * PP * PP)  // 3,145,728
#define SLICE_VEC4  (SLICE_ELEMS / 4)                       // 786,432
#define BLOCKS_PER_SLICE (SLICE_VEC4 / 256)                 // 3,072

typedef float f32x4 __attribute__((ext_vector_type(4)));

__global__ __launch_bounds__(256) void cut_patches_kernel(
    const float* __restrict__ imgs,
    const int*   __restrict__ pih,
    const int*   __restrict__ piw,
    float*       __restrict__ out_patches,
    float*       __restrict__ out_inds)
{
    int xcd = blockIdx.x & (NXCD - 1);
    int bid = blockIdx.x >> 3;
    int s   = bid * blockDim.x + threadIdx.x;

    int e = s << 2;
    // slice decomposition (pw fastest): wave = 256 elems = one (proj,nl,c),
    // so proj/w0/t below are wave-uniform.
    int pw  = e & 15;                 // multiple of 4
    int k4  = pw >> 2;                // which vec4 chunk of the patch row
    int tmp = e >> 4;
    int ph  = tmp & 15;
    tmp >>= 4;
    int c   = tmp % 3;
    tmp    /= 3;
    int nl  = tmp & (IMGS_PER_XCD - 1);
    int proj = tmp >> 3;
    int n   = (xcd << 3) | nl;

    int h0 = pih[proj];
    int w0 = piw[proj];

    int hh = h0 + ph;
    if (hh >= HH) hh -= HH;

    // base float index of this image row; multiple of 128 (so base>>2 is chunk-aligned)
    int base = hh * WWID + c * (HH * WWID) + n * (CCH * HH * WWID);
    const f32x4* rowv = reinterpret_cast<const f32x4*>(imgs) + (base >> 2); // 32 chunks/row

    int cb = (w0 >> 2) + k4;          // source chunk (pre-wrap)
    int t  = w0 & 3;                  // wave-uniform misalignment

    // Aligned vec4 gather + wave-uniform recombine (compile-time swizzles only).
    f32x4 A = rowv[cb & 31];
    f32x4 vals;
    if (t == 0) {
        vals = A;
    } else {
        f32x4 B = rowv[(cb + 1) & 31];
        if (t == 1)      vals = (f32x4){A.y, A.z, A.w, B.x};
        else if (t == 2) vals = (f32x4){A.z, A.w, B.x, B.y};
        else             vals = (f32x4){A.w, B.x, B.y, B.z};
    }

    // linear indices (exact in f32: lin < 2^24)
    f32x4 inds;
#pragma unroll
    for (int j = 0; j < 4; ++j) {
        int w = w0 + pw + j;
        if (w >= WWID) w -= WWID;
        inds[j] = (float)(base + w);
    }

    // output vec index (global layout [proj][n][c][ph][pw])
    int oelem = (((proj * NIMG + n) * CCH + c) << 8) | (ph << 4) | pw;
    int ovec  = oelem >> 2;

    __builtin_nontemporal_store(vals, reinterpret_cast<f32x4*>(out_patches) + ovec);
    __builtin_nontemporal_store(inds, reinterpret_cast<f32x4*>(out_inds) + ovec);
}

extern "C" void kernel_launch(void* const* d_in, const int* in_sizes, int n_in,
                              void* d_out, int out_size, void* d_ws, size_t ws_size,
                              hipStream_t stream) {
    const float* imgs = (const float*)d_in[0];
    const int*   pih  = (const int*)d_in[1];
    const int*   piw  = (const int*)d_in[2];

    float* out_patches = (float*)d_out;
    float* out_inds    = (float*)d_out + TOTAL_ELEMS;

    const int block = 256;
    const int grid  = BLOCKS_PER_SLICE * NXCD;
    cut_patches_kernel<<<grid, block, 0, stream>>>(imgs, pih, piw, out_patches, out_inds);
}

// Round 5
// 37.680 us; speedup vs baseline: 1.6066x; 1.0815x over previous
//
#include <hip/hip_runtime.h>

// Problem constants (match reference)
#define HH    128
#define WWID  128
#define CCH   3
#define PP    16
#define NIMG  64
#define NPROJ 512
#define NXCD  8
#define IMGS_PER_XCD (NIMG / NXCD)

#define TOTAL_ELEMS 25165824
#define SLICE_ELEMS (NPROJ * IMGS_PER_XCD * CCH * PP * PP)  // 3,145,728
#define SLICE_VEC4  (SLICE_ELEMS / 4)                       // 786,432
#define BLOCKS_PER_SLICE (SLICE_VEC4 / 256)                 // 3,072

typedef float f32x4 __attribute__((ext_vector_type(4)));

__global__ __launch_bounds__(256) void cut_patches_kernel(
    const float* __restrict__ imgs,
    const int*   __restrict__ pih,
    const int*   __restrict__ piw,
    float*       __restrict__ out_patches,
    float*       __restrict__ out_inds)
{
    int xcd = blockIdx.x & (NXCD - 1);
    int bid = blockIdx.x >> 3;
    int s   = bid * blockDim.x + threadIdx.x;

    int e = s << 2;
    // slice decomposition (pw fastest): wave = 256 elems = one (proj,nl,c),
    // so proj/w0/t below are wave-uniform.
    int pw  = e & 15;                 // multiple of 4
    int k4  = pw >> 2;                // which vec4 chunk of the patch row
    int tmp = e >> 4;
    int ph  = tmp & 15;
    tmp >>= 4;
    int c   = tmp % 3;
    tmp    /= 3;
    int nl  = tmp & (IMGS_PER_XCD - 1);
    int proj = tmp >> 3;
    int n   = (xcd << 3) | nl;

    int h0 = pih[proj];
    int w0 = piw[proj];

    int hh = h0 + ph;
    if (hh >= HH) hh -= HH;

    // base float index of this image row; multiple of 128 (so base>>2 is chunk-aligned)
    int base = hh * WWID + c * (HH * WWID) + n * (CCH * HH * WWID);
    const f32x4* rowv = reinterpret_cast<const f32x4*>(imgs) + (base >> 2); // 32 chunks/row

    int cb = (w0 >> 2) + k4;          // source chunk (pre-wrap)
    int t  = w0 & 3;                  // wave-uniform misalignment

    // Aligned vec4 gather + wave-uniform recombine (compile-time swizzles only).
    f32x4 A = rowv[cb & 31];
    f32x4 vals;
    if (t == 0) {
        vals = A;
    } else {
        f32x4 B = rowv[(cb + 1) & 31];
        if (t == 1)      vals = (f32x4){A.y, A.z, A.w, B.x};
        else if (t == 2) vals = (f32x4){A.z, A.w, B.x, B.y};
        else             vals = (f32x4){A.w, B.x, B.y, B.z};
    }

    // linear indices (exact in f32: lin < 2^24)
    f32x4 inds;
#pragma unroll
    for (int j = 0; j < 4; ++j) {
        int w = w0 + pw + j;
        if (w >= WWID) w -= WWID;
        inds[j] = (float)(base + w);
    }

    // output vec index (global layout [proj][n][c][ph][pw])
    int oelem = (((proj * NIMG + n) * CCH + c) << 8) | (ph << 4) | pw;
    int ovec  = oelem >> 2;

    // A/B vs R4: plain stores instead of nontemporal (fills hit 6.9 TB/s w/ plain).
    reinterpret_cast<f32x4*>(out_patches)[ovec] = vals;
    reinterpret_cast<f32x4*>(out_inds)[ovec]    = inds;
}

extern "C" void kernel_launch(void* const* d_in, const int* in_sizes, int n_in,
                              void* d_out, int out_size, void* d_ws, size_t ws_size,
                              hipStream_t stream) {
    const float* imgs = (const float*)d_in[0];
    const int*   pih  = (const int*)d_in[1];
    const int*   piw  = (const int*)d_in[2];

    float* out_patches = (float*)d_out;
    float* out_inds    = (float*)d_out + TOTAL_ELEMS;

    const int block = 256;
    const int grid  = BLOCKS_PER_SLICE * NXCD;
    cut_patches_kernel<<<grid, block, 0, stream>>>(imgs, pih, piw, out_patches, out_inds);
}